// Round 5
// baseline (890.758 us; speedup 1.0000x reference)
//
#include <hip/hip_runtime.h>
#include <math.h>

typedef __attribute__((ext_vector_type(4))) float f32x4;
typedef long frag8;   // 8 fp8 (e4m3) bytes = 2 VGPRs, MFMA A/B operand

#define AS1 __attribute__((address_space(1)))
#define AS3 __attribute__((address_space(3)))

#define N_ROWS 8192
#define DFULL 768
#define LOG2E 1.4426950408889634f
#define KSC (LOG2E / 0.05f)
#define NEGSH (-28.853900817779268f)   // -20 * log2(e)
#define LN2 0.6931471805599453f

__device__ __forceinline__ void gload_lds16(const void* g, void* l) {
  __builtin_amdgcn_global_load_lds((const AS1 void*)g, (AS3 void*)l, 16, 0, 0);
}

// ---------------- kernel 1: per-row prefix norms + fp8 e4m3 convert ----------------
// 192 threads, 4 elems/thread. Norms from fp32 (matches reference); data quantized to fp8.
__global__ __launch_bounds__(192) void mcl_prep(
    const float* __restrict__ e1, const float* __restrict__ e2,
    char* __restrict__ h1, char* __restrict__ h2,
    float* __restrict__ inv1, float* __restrict__ inv2)
{
  const int b = blockIdx.x;
  const int mat = b >> 13, row = b & (N_ROWS - 1);
  const float* src = (mat ? e2 : e1) + (size_t)row * DFULL;
  char* dst = (mat ? h2 : h1) + (size_t)row * DFULL;
  float* invo = mat ? inv2 : inv1;
  const int t = threadIdx.x;
  const int e0 = t * 4;

  const f32x4 v = *(const f32x4*)(src + e0);
  const float s = v[0]*v[0] + v[1]*v[1] + v[2]*v[2] + v[3]*v[3];
  float p0 = (e0 < 64)  ? s : 0.f;
  float p1 = (e0 < 128) ? s : 0.f;
  float p2 = (e0 < 256) ? s : 0.f;
  float p3 = (e0 < 512) ? s : 0.f;
  float p4 = s;

  const int lo = __builtin_amdgcn_cvt_pk_fp8_f32(v[0], v[1], 0, false);
  const int pk = __builtin_amdgcn_cvt_pk_fp8_f32(v[2], v[3], lo, true);
  *(int*)(dst + e0) = pk;

#pragma unroll
  for (int off = 32; off > 0; off >>= 1) {
    p0 += __shfl_down(p0, off, 64);
    p1 += __shfl_down(p1, off, 64);
    p2 += __shfl_down(p2, off, 64);
    p3 += __shfl_down(p3, off, 64);
    p4 += __shfl_down(p4, off, 64);
  }
  __shared__ float red[3][5];
  const int lane = t & 63, w = t >> 6;
  if (lane == 0) { red[w][0]=p0; red[w][1]=p1; red[w][2]=p2; red[w][3]=p3; red[w][4]=p4; }
  __syncthreads();
  if (t == 0) {
#pragma unroll
    for (int q = 0; q < 5; ++q) {
      const float sum = red[0][q] + red[1][q] + red[2][q];
      invo[q * N_ROWS + row] = 1.f / fmaxf(sqrtf(sum), 1e-8f);
    }
  }
}

// ---------------- kernel 2: fp8 cumulative GEMM + checkpoint softmax partials ----------------
// 256 threads = 4 waves (2x2), 128x128 tile, BK=64 (fp8 => 8KB per matrix per buffer).
// Double-buffered (32KB LDS), ONE barrier per chunk: STAGE(next) issued before COMPUTE(cur).
// Swapped-operand MFMA: acc[n][m] = mfma(bf[n], af[m], .) ->
//   i (softmax row) = wr*64 + m*16 + (lane&15)         [lane-low]
//   j (reduce axis) = wc*64 + n*16 + (lane>>4)*4 + rg  [register + lane-hi]
// 8B-slot XOR swizzle with mask (row&6): keeps 16B staging granules source-contiguous,
// b64 fragment reads <=2-way (free). Rowsums kept in registers (static idx), combined at end.
__global__ __launch_bounds__(256, 4) void mcl_main(
    const char* __restrict__ h1, const char* __restrict__ h2,
    const float* __restrict__ inv1, const float* __restrict__ inv2,
    float* __restrict__ diag, float* __restrict__ partial)
{
  __shared__ __align__(16) char smem[32768];
  // [0,8K) sA buf0 | [8K,16K) sA buf1 | [16K,24K) sB buf0 | [24K,32K) sB buf1

  const int tid = threadIdx.x;
  const int lane = tid & 63, wid = tid >> 6;
  const int wr = wid >> 1, wc = wid & 1;
  const int l15 = lane & 15, lh = lane >> 4;

  // XCD-chunked + 8x8-supertile swizzle (bijective: 4096 = 8 * 512)
  const int id = blockIdx.x;
  const int nid = (id & 7) * 512 + (id >> 3);
  const int st = nid >> 6, tt = nid & 63;
  const int bi = ((st >> 3) << 3) + (tt >> 3);
  const int bj = ((st & 7) << 3) + (tt & 7);
  const int rowA0 = bi * 128, rowB0 = bj * 128;

  f32x4 acc[4][4];  // [n][m]
#pragma unroll
  for (int n = 0; n < 4; ++n)
#pragma unroll
    for (int m = 0; m < 4; ++m) acc[n][m] = (f32x4)0.f;
  float rowAcc[5][4];
#pragma unroll
  for (int d = 0; d < 5; ++d)
#pragma unroll
    for (int m = 0; m < 4; ++m) rowAcc[d][m] = 0.f;

#define STAGE(BUF, CKI) {                                                      \
    _Pragma("unroll")                                                          \
    for (int r = 0; r < 2; ++r) {                                              \
      const int blk = r * 4 + wid;               /* 1KB wave-block 0..7 */     \
      const int gr = (blk << 6) + lane;          /* 16B granule 0..511 */      \
      const int grow = gr >> 2, gg = gr & 3;                                   \
      const int koff = (CKI) * 64 + ((((gg) << 1) ^ (grow & 6)) << 3);         \
      gload_lds16(h1 + (size_t)(rowA0 + grow) * DFULL + koff,                  \
                  smem + ((BUF) << 13) + (blk << 10));                         \
      gload_lds16(h2 + (size_t)(rowB0 + grow) * DFULL + koff,                  \
                  smem + 16384 + ((BUF) << 13) + (blk << 10));                 \
    } }

#define COMPUTE(BUF) {                                                         \
    const char* pA = smem + ((BUF) << 13);                                     \
    const char* pB = smem + 16384 + ((BUF) << 13);                             \
    _Pragma("unroll")                                                          \
    for (int ks = 0; ks < 2; ++ks) {                                           \
      frag8 af[4], bf[4];                                                      \
      _Pragma("unroll")                                                        \
      for (int m = 0; m < 4; ++m) {                                            \
        const int rowa = wr * 64 + m * 16 + l15;                               \
        af[m] = *(const frag8*)(pA + rowa * 64 +                               \
                 ((((ks << 2) + lh) ^ (rowa & 6)) << 3));                      \
        const int rowb = wc * 64 + m * 16 + l15;                               \
        bf[m] = *(const frag8*)(pB + rowb * 64 +                               \
                 ((((ks << 2) + lh) ^ (rowb & 6)) << 3));                      \
      }                                                                        \
      _Pragma("unroll")                                                        \
      for (int n = 0; n < 4; ++n)                                              \
        _Pragma("unroll")                                                      \
        for (int m = 0; m < 4; ++m)                                            \
          acc[n][m] = __builtin_amdgcn_mfma_f32_16x16x32_fp8_fp8(              \
              bf[n], af[m], acc[n][m], 0, 0, 0);                               \
    } }

#define EPI(DCP) {                                                             \
    float s1K[4];                                                              \
    _Pragma("unroll")                                                          \
    for (int m = 0; m < 4; ++m)                                                \
      s1K[m] = inv1[(DCP) * N_ROWS + rowA0 + wr * 64 + m * 16 + l15] * KSC;    \
    _Pragma("unroll")                                                          \
    for (int n = 0; n < 4; ++n) {                                              \
      const f32x4 s2 = *(const f32x4*)(inv2 + (DCP) * N_ROWS + rowB0 +         \
                                       wc * 64 + n * 16 + (lh << 2));          \
      _Pragma("unroll")                                                        \
      for (int m = 0; m < 4; ++m) {                                            \
        const f32x4 u = acc[n][m] * s2 * s1K[m] + NEGSH;                       \
        rowAcc[(DCP)][m] += __builtin_amdgcn_exp2f(u[0]) +                     \
                            __builtin_amdgcn_exp2f(u[1]) +                     \
                            __builtin_amdgcn_exp2f(u[2]) +                     \
                            __builtin_amdgcn_exp2f(u[3]);                      \
      }                                                                        \
    }                                                                          \
    if (bi == bj && wr == wc && lh == (l15 >> 2)) {                            \
      const int rgd = l15 & 3;                                                 \
      _Pragma("unroll")                                                        \
      for (int m = 0; m < 4; ++m) {                                            \
        const float s2d = inv2[(DCP) * N_ROWS + rowB0 + wc * 64 + m * 16 + l15];\
        diag[(DCP) * N_ROWS + rowA0 + wr * 64 + m * 16 + l15] =                \
            acc[m][m][rgd] * s1K[m] * s2d * LN2;                               \
      }                                                                        \
    } }

#define CHUNK(CK, DCP) {                                                       \
    if ((CK) < 11) { STAGE((((CK) + 1) & 1), ((CK) + 1)); }                    \
    COMPUTE(((CK) & 1));                                                       \
    if ((DCP) >= 0) { EPI((((DCP) < 0) ? 0 : (DCP))); }                        \
    __syncthreads(); }

  STAGE(0, 0);
  __syncthreads();

  CHUNK(0, 0);  CHUNK(1, 1);  CHUNK(2, -1);  CHUNK(3, 2);
  CHUNK(4, -1); CHUNK(5, -1); CHUNK(6, -1);  CHUNK(7, 3);
  CHUNK(8, -1); CHUNK(9, -1); CHUNK(10, -1); CHUNK(11, 4);

#undef CHUNK
#undef EPI
#undef COMPUTE
#undef STAGE

  // deferred butterfly over lane-hi (j sub-axis), then combine wc halves via reused LDS
  float* scr = (float*)smem;  // [wc][d][128] = 2*5*128 floats, safe after final barrier
#pragma unroll
  for (int d = 0; d < 5; ++d)
#pragma unroll
    for (int m = 0; m < 4; ++m) {
      float v = rowAcc[d][m];
      v += __shfl_xor(v, 16, 64);
      v += __shfl_xor(v, 32, 64);
      if (lh == 0) scr[(wc * 5 + d) * 128 + wr * 64 + m * 16 + l15] = v;
    }
  __syncthreads();
  for (int x = tid; x < 5 * 128; x += 256) {
    const int d = x >> 7, r = x & 127;
    partial[((size_t)bj * 5 + d) * N_ROWS + rowA0 + r] =
        scr[d * 128 + r] + scr[(5 + d) * 128 + r];
  }
}

// ---------------- kernel 3: final reduction ----------------
__global__ __launch_bounds__(256) void mcl_reduce(
    const float* __restrict__ partial, const float* __restrict__ diag,
    float* __restrict__ out)
{
  const int item = blockIdx.x * 256 + threadIdx.x;  // 0..40959
  const int d = item >> 13;
  const int i = item & (N_ROWS - 1);
  float s = 0.f;
#pragma unroll 4
  for (int bj = 0; bj < 64; ++bj)
    s += partial[((size_t)bj * 5 + d) * N_ROWS + i];
  float term = (20.0f + logf(s) - diag[d * N_ROWS + i]) * (1.0f / 8192.0f);
#pragma unroll
  for (int off = 32; off > 0; off >>= 1) term += __shfl_down(term, off, 64);
  __shared__ float red[4];
  const int lane = threadIdx.x & 63, w = threadIdx.x >> 6;
  if (lane == 0) red[w] = term;
  __syncthreads();
  if (threadIdx.x == 0) atomicAdd(out, red[0] + red[1] + red[2] + red[3]);
}

// ---------------- launcher ----------------
extern "C" void kernel_launch(void* const* d_in, const int* in_sizes, int n_in,
                              void* d_out, int out_size, void* d_ws, size_t ws_size,
                              hipStream_t stream) {
  const float* e1 = (const float*)d_in[0];
  const float* e2 = (const float*)d_in[1];
  char* ws = (char*)d_ws;

  const size_t HBYTES = (size_t)N_ROWS * DFULL;                 // 6,291,456 (fp8)
  const size_t IBYTES = (size_t)5 * N_ROWS * sizeof(float);     //   163,840
  char*  h1      = ws;
  char*  h2      = ws + HBYTES;
  float* inv1    = (float*)(ws + 2 * HBYTES);
  float* inv2    = (float*)(ws + 2 * HBYTES + IBYTES);
  float* diag    = (float*)(ws + 2 * HBYTES + 2 * IBYTES);
  float* partial = (float*)(ws + 2 * HBYTES + 3 * IBYTES);      // 64*5*8192*4 = 10,485,760
  const size_t NEED = 2 * HBYTES + 3 * IBYTES + (size_t)64 * 5 * N_ROWS * sizeof(float);
  if (ws_size < NEED) return;

  hipMemsetAsync(d_out, 0, sizeof(float) * out_size, stream);
  mcl_prep<<<2 * N_ROWS, 192, 0, stream>>>(e1, e2, h1, h2, inv1, inv2);
  mcl_main<<<4096, 256, 0, stream>>>(h1, h2, inv1, inv2, diag, partial);
  mcl_reduce<<<160, 256, 0, stream>>>(partial, diag, (float*)d_out);
}

// Round 6
// 153.661 us; speedup vs baseline: 5.7969x; 5.7969x over previous
//
#include <hip/hip_runtime.h>
#include <math.h>

typedef __attribute__((ext_vector_type(4))) float f32x4;
typedef __attribute__((ext_vector_type(2))) long longx2;  // 16B = two fp8 MFMA operands

#define AS1 __attribute__((address_space(1)))
#define AS3 __attribute__((address_space(3)))

#define N_ROWS 8192
#define DFULL 768
#define LOG2E 1.4426950408889634f
#define KSC (LOG2E / 0.05f)
#define NEGSH (-28.853900817779268f)   // -20 * log2(e)
#define LN2 0.6931471805599453f

__device__ __forceinline__ void gload_lds16(const void* g, void* l) {
  __builtin_amdgcn_global_load_lds((const AS1 void*)g, (AS3 void*)l, 16, 0, 0);
}

// ---------------- kernel 1: per-row prefix norms + fp8 e4m3 convert (k-interleaved layout) ----
// Layout per 128-byte k-chunk: granule g = t*4+h (16B) holds slots {ks=2t,lh=h} (low 8B)
// and {ks=2t+1,lh=h} (high 8B), i.e. original k = t*64 + par*32 + h*8 + b.
__global__ __launch_bounds__(192) void mcl_prep(
    const float* __restrict__ e1, const float* __restrict__ e2,
    char* __restrict__ h1, char* __restrict__ h2,
    float* __restrict__ inv1, float* __restrict__ inv2)
{
  const int b = blockIdx.x;
  const int mat = b >> 13, row = b & (N_ROWS - 1);
  const float* src = (mat ? e2 : e1) + (size_t)row * DFULL;
  char* dst = (mat ? h2 : h1) + (size_t)row * DFULL;
  float* invo = mat ? inv2 : inv1;
  const int t = threadIdx.x;
  const int k = t * 4;

  const f32x4 v = *(const f32x4*)(src + k);
  const float s = v[0]*v[0] + v[1]*v[1] + v[2]*v[2] + v[3]*v[3];
  float p0 = (k < 64)  ? s : 0.f;
  float p1 = (k < 128) ? s : 0.f;
  float p2 = (k < 256) ? s : 0.f;
  float p3 = (k < 512) ? s : 0.f;
  float p4 = s;

  const int lo = __builtin_amdgcn_cvt_pk_fp8_f32(v[0], v[1], 0, false);
  const int pk = __builtin_amdgcn_cvt_pk_fp8_f32(v[2], v[3], lo, true);
  // permuted destination position
  const int chunk = k >> 7, c = k & 127;
  const int ks = c >> 5, h = (c >> 3) & 3;
  const int g = ((ks >> 1) << 2) + h;
  const int dpos = (chunk << 7) + (g << 4) + ((ks & 1) << 3) + (c & 4);
  *(int*)(dst + dpos) = pk;

#pragma unroll
  for (int off = 32; off > 0; off >>= 1) {
    p0 += __shfl_down(p0, off, 64);
    p1 += __shfl_down(p1, off, 64);
    p2 += __shfl_down(p2, off, 64);
    p3 += __shfl_down(p3, off, 64);
    p4 += __shfl_down(p4, off, 64);
  }
  __shared__ float red[3][5];
  const int lane = t & 63, w = t >> 6;
  if (lane == 0) { red[w][0]=p0; red[w][1]=p1; red[w][2]=p2; red[w][3]=p3; red[w][4]=p4; }
  __syncthreads();
  if (t == 0) {
#pragma unroll
    for (int q = 0; q < 5; ++q) {
      const float sum = red[0][q] + red[1][q] + red[2][q];
      invo[q * N_ROWS + row] = 1.f / fmaxf(sqrtf(sum), 1e-8f);
    }
  }
}

// ---------------- kernel 2: fp8 cumulative GEMM + checkpoint softmax partials ----------------
// 256 threads = 4 waves (2x2), per-wave 64x64. Single-buffer 2-barrier schedule (round-4
// proven), BK=128 fp8 (128B rows, 8 granules of 16B, XOR-(row&7) swizzle = round-4 geometry,
// zero conflicts). One b128 read feeds TWO MFMA K-steps via the k-interleaved layout.
// Swapped-operand MFMA: acc[n][m] = mfma(bf[n], af[m], .) ->
//   i (softmax row) = wr*64 + m*16 + (lane&15)         [lane-low]
//   j (reduce axis) = wc*64 + n*16 + (lane>>4)*4 + rg  [register + lane-hi]
__global__ __launch_bounds__(256, 2) void mcl_main(
    const char* __restrict__ h1, const char* __restrict__ h2,
    const float* __restrict__ inv1, const float* __restrict__ inv2,
    float* __restrict__ diag, float* __restrict__ partial)
{
  __shared__ __align__(16) char sA[128 * 128];
  __shared__ __align__(16) char sB[128 * 128];
  __shared__ float rowsumW[2][5][128];   // [wc][dim][row]

  const int tid = threadIdx.x;
  const int lane = tid & 63, wid = tid >> 6;
  const int wr = wid >> 1, wc = wid & 1;
  const int l15 = lane & 15, lh = lane >> 4;

  // XCD-chunked + 8x8-supertile swizzle (bijective: 4096 = 8 * 512)
  const int id = blockIdx.x;
  const int nid = (id & 7) * 512 + (id >> 3);
  const int st = nid >> 6, tt = nid & 63;
  const int bi = ((st >> 3) << 3) + (tt >> 3);
  const int bj = ((st & 7) << 3) + (tt & 7);
  const int rowA0 = bi * 128, rowB0 = bj * 128;

  for (int x = tid; x < 2 * 5 * 128; x += 256) ((float*)rowsumW)[x] = 0.f;

  f32x4 acc[4][4];  // [n][m]
#pragma unroll
  for (int n = 0; n < 4; ++n)
#pragma unroll
    for (int m = 0; m < 4; ++m) acc[n][m] = (f32x4)0.f;

#pragma unroll 1
  for (int ck = 0; ck < 6; ++ck) {
    // ---- stage 128x128B of A and B (linear LDS dest; swizzle via global source) ----
#pragma unroll
    for (int r = 0; r < 4; ++r) {
      const int gi = ((r * 4 + wid) << 6) + lane;   // granule 0..1023
      const int grow = gi >> 3, g = gi & 7;
      const int off = (ck << 7) + ((g ^ (grow & 7)) << 4);
      gload_lds16(h1 + (size_t)(rowA0 + grow) * DFULL + off,
                  sA + ((size_t)(r * 4 + wid) << 10));
      gload_lds16(h2 + (size_t)(rowB0 + grow) * DFULL + off,
                  sB + ((size_t)(r * 4 + wid) << 10));
    }
    __syncthreads();
    // ---- 2 half-chunks (th), each = one b128 read set feeding 2 MFMA K-steps ----
#pragma unroll
    for (int th = 0; th < 2; ++th) {
      longx2 af[4], bf[4];
#pragma unroll
      for (int m = 0; m < 4; ++m) {
        const int rowa = wr * 64 + m * 16 + l15;
        af[m] = *(const longx2*)(sA + rowa * 128 + ((((th << 2) + lh) ^ (rowa & 7)) << 4));
        const int rowb = wc * 64 + m * 16 + l15;
        bf[m] = *(const longx2*)(sB + rowb * 128 + ((((th << 2) + lh) ^ (rowb & 7)) << 4));
      }
#pragma unroll
      for (int s = 0; s < 2; ++s)
#pragma unroll
        for (int n = 0; n < 4; ++n)
#pragma unroll
          for (int m = 0; m < 4; ++m)
            acc[n][m] = __builtin_amdgcn_mfma_f32_16x16x32_fp8_fp8(
                bf[n][s], af[m][s], acc[n][m], 0, 0, 0);

      // ---- checkpoint? cumulative K = ck*128 + (th+1)*64 ----
      const int kdone = (ck << 7) + ((th + 1) << 6);
      int dcp = -1;
      if (kdone == 64) dcp = 0;
      else if (kdone == 128) dcp = 1;
      else if (kdone == 256) dcp = 2;
      else if (kdone == 512) dcp = 3;
      else if (kdone == 768) dcp = 4;
      if (dcp >= 0) {
        float s1K[4];
#pragma unroll
        for (int m = 0; m < 4; ++m)
          s1K[m] = inv1[dcp * N_ROWS + rowA0 + wr * 64 + m * 16 + l15] * KSC;
        float rp[4] = {0.f, 0.f, 0.f, 0.f};
#pragma unroll
        for (int n = 0; n < 4; ++n) {
          const f32x4 s2 = *(const f32x4*)(inv2 + dcp * N_ROWS + rowB0 +
                                           wc * 64 + n * 16 + (lh << 2));
#pragma unroll
          for (int m = 0; m < 4; ++m) {
            const f32x4 u = acc[n][m] * s2 * s1K[m] + NEGSH;
            rp[m] += __builtin_amdgcn_exp2f(u[0]) + __builtin_amdgcn_exp2f(u[1]) +
                     __builtin_amdgcn_exp2f(u[2]) + __builtin_amdgcn_exp2f(u[3]);
          }
        }
#pragma unroll
        for (int m = 0; m < 4; ++m) {
          rp[m] += __shfl_xor(rp[m], 16, 64);
          rp[m] += __shfl_xor(rp[m], 32, 64);
        }
        if (lh == 0) {
#pragma unroll
          for (int m = 0; m < 4; ++m)
            rowsumW[wc][dcp][wr * 64 + m * 16 + l15] += rp[m];
        }
        if (bi == bj && wr == wc && lh == (l15 >> 2)) {
          const int rgd = l15 & 3;
#pragma unroll
          for (int m = 0; m < 4; ++m) {
            const float s2d = inv2[dcp * N_ROWS + rowB0 + wc * 64 + m * 16 + l15];
            diag[dcp * N_ROWS + rowA0 + wr * 64 + m * 16 + l15] =
                acc[m][m][rgd] * s1K[m] * s2d * LN2;
          }
        }
      }
    }
    __syncthreads();
  }

  // write per-(column-block) partial sumexp
  for (int x = tid; x < 5 * 128; x += 256) {
    const int d = x >> 7, r = x & 127;
    partial[((size_t)bj * 5 + d) * N_ROWS + rowA0 + r] = rowsumW[0][d][r] + rowsumW[1][d][r];
  }
}

// ---------------- kernel 3: final reduction ----------------
__global__ __launch_bounds__(256) void mcl_reduce(
    const float* __restrict__ partial, const float* __restrict__ diag,
    float* __restrict__ out)
{
  const int item = blockIdx.x * 256 + threadIdx.x;  // 0..40959
  const int d = item >> 13;
  const int i = item & (N_ROWS - 1);
  float s = 0.f;
#pragma unroll 4
  for (int bj = 0; bj < 64; ++bj)
    s += partial[((size_t)bj * 5 + d) * N_ROWS + i];
  float term = (20.0f + logf(s) - diag[d * N_ROWS + i]) * (1.0f / 8192.0f);
#pragma unroll
  for (int off = 32; off > 0; off >>= 1) term += __shfl_down(term, off, 64);
  __shared__ float red[4];
  const int lane = threadIdx.x & 63, w = threadIdx.x >> 6;
  if (lane == 0) red[w] = term;
  __syncthreads();
  if (threadIdx.x == 0) atomicAdd(out, red[0] + red[1] + red[2] + red[3]);
}

// ---------------- launcher ----------------
extern "C" void kernel_launch(void* const* d_in, const int* in_sizes, int n_in,
                              void* d_out, int out_size, void* d_ws, size_t ws_size,
                              hipStream_t stream) {
  const float* e1 = (const float*)d_in[0];
  const float* e2 = (const float*)d_in[1];
  char* ws = (char*)d_ws;

  const size_t HBYTES = (size_t)N_ROWS * DFULL;                 // 6,291,456 (fp8)
  const size_t IBYTES = (size_t)5 * N_ROWS * sizeof(float);     //   163,840
  char*  h1      = ws;
  char*  h2      = ws + HBYTES;
  float* inv1    = (float*)(ws + 2 * HBYTES);
  float* inv2    = (float*)(ws + 2 * HBYTES + IBYTES);
  float* diag    = (float*)(ws + 2 * HBYTES + 2 * IBYTES);
  float* partial = (float*)(ws + 2 * HBYTES + 3 * IBYTES);      // 64*5*8192*4 = 10,485,760
  const size_t NEED = 2 * HBYTES + 3 * IBYTES + (size_t)64 * 5 * N_ROWS * sizeof(float);
  if (ws_size < NEED) return;

  hipMemsetAsync(d_out, 0, sizeof(float) * out_size, stream);
  mcl_prep<<<2 * N_ROWS, 192, 0, stream>>>(e1, e2, h1, h2, inv1, inv2);
  mcl_main<<<4096, 256, 0, stream>>>(h1, h2, inv1, inv2, diag, partial);
  mcl_reduce<<<160, 256, 0, stream>>>(partial, diag, (float*)d_out);
}

// Round 8
// 145.214 us; speedup vs baseline: 6.1341x; 1.0582x over previous
//
#include <hip/hip_runtime.h>
#include <math.h>

typedef __attribute__((ext_vector_type(4))) float f32x4;
typedef __attribute__((ext_vector_type(2))) long longx2;  // 16B = two fp8 MFMA operands

#define N_ROWS 8192
#define DFULL 768
#define LOG2E 1.4426950408889634f
#define KSC (LOG2E / 0.05f)
#define NEGSH (-28.853900817779268f)   // -20 * log2(e)
#define LN2 0.6931471805599453f
#define PLB ((size_t)N_ROWS * 16)      // bytes per 16B-granule plane

// ---------------- kernel 1: per-row prefix norms + fp8 e4m3 convert (plane-major layout) ----
// Fragment layout: granule plane p = (k>>7)*8 + ((k>>6)&1)*4 + ((k>>3)&3) holds, at
// row*16 + ((k>>5)&1)*8 + (k&7), the fp8 byte for (row,k). One 16B read at (p,row)
// yields the two 8B MFMA k-slot operands (s=0 low, s=1 high) for lane-slot lh=(k>>3)&3.
// Same permutation for A and B => dot products invariant.
__global__ __launch_bounds__(192) void mcl_prep(
    const float* __restrict__ e1, const float* __restrict__ e2,
    char* __restrict__ h1, char* __restrict__ h2,
    float* __restrict__ inv1, float* __restrict__ inv2)
{
  const int b = blockIdx.x;
  const int mat = b >> 13, row = b & (N_ROWS - 1);
  const float* src = (mat ? e2 : e1) + (size_t)row * DFULL;
  char* dst = mat ? h2 : h1;
  float* invo = mat ? inv2 : inv1;
  const int t = threadIdx.x;
  const int k = t * 4;

  const f32x4 v = *(const f32x4*)(src + k);
  const float s = v[0]*v[0] + v[1]*v[1] + v[2]*v[2] + v[3]*v[3];
  float p0 = (k < 64)  ? s : 0.f;
  float p1 = (k < 128) ? s : 0.f;
  float p2 = (k < 256) ? s : 0.f;
  float p3 = (k < 512) ? s : 0.f;
  float p4 = s;

  const int lo = __builtin_amdgcn_cvt_pk_fp8_f32(v[0], v[1], 0, false);
  const int pk = __builtin_amdgcn_cvt_pk_fp8_f32(v[2], v[3], lo, true);
  const int plane = ((k >> 7) << 3) + (((k >> 6) & 1) << 2) + ((k >> 3) & 3);
  const int inb = (((k >> 5) & 1) << 3) + (k & 7);
  *(int*)(dst + (size_t)plane * PLB + (size_t)row * 16 + inb) = pk;

#pragma unroll
  for (int off = 32; off > 0; off >>= 1) {
    p0 += __shfl_down(p0, off, 64);
    p1 += __shfl_down(p1, off, 64);
    p2 += __shfl_down(p2, off, 64);
    p3 += __shfl_down(p3, off, 64);
    p4 += __shfl_down(p4, off, 64);
  }
  __shared__ float red[3][5];
  const int lane = t & 63, w = t >> 6;
  if (lane == 0) { red[w][0]=p0; red[w][1]=p1; red[w][2]=p2; red[w][3]=p3; red[w][4]=p4; }
  __syncthreads();
  if (t == 0) {
#pragma unroll
    for (int q = 0; q < 5; ++q) {
      const float sum = red[0][q] + red[1][q] + red[2][q];
      invo[q * N_ROWS + row] = 1.f / fmaxf(sqrtf(sum), 1e-8f);
    }
  }
}

// ---------------- kernel 2: fp8 GEMM direct-from-L2 + checkpoint softmax partials --------
// 256 threads = 4 waves (2x2), per-wave 64x64, NO LDS in the hot loop, NO barriers:
// fragments are loaded straight from the plane-major global layout (L2/L3-resident,
// 256B-contiguous per load). Waves fully independent -> MFMA/VALU/trans overlap.
// Swapped-operand MFMA: acc[n][m] = mfma(bf[n], af[m], .) ->
//   i (softmax row) = wr*64 + m*16 + (lane&15)         [lane-low]
//   j (reduce axis) = wc*64 + n*16 + (lane>>4)*4 + rg  [register + lane-hi]
__global__ __launch_bounds__(256, 2) void mcl_main(
    const char* __restrict__ h1, const char* __restrict__ h2,
    const float* __restrict__ inv1, const float* __restrict__ inv2,
    float* __restrict__ diag, float* __restrict__ partial)
{
  __shared__ float scr[2][5][128];   // end-of-kernel combine only (5 KB)

  const int tid = threadIdx.x;
  const int lane = tid & 63, wid = tid >> 6;
  const int wr = wid >> 1, wc = wid & 1;
  const int l15 = lane & 15, lh = lane >> 4;

  // XCD-chunked + 8x8-supertile swizzle (bijective: 4096 = 8 * 512)
  const int id = blockIdx.x;
  const int nid = (id & 7) * 512 + (id >> 3);
  const int st = nid >> 6, tt = nid & 63;
  const int bi = ((st >> 3) << 3) + (tt >> 3);
  const int bj = ((st & 7) << 3) + (tt & 7);
  const int rowA0 = bi * 128, rowB0 = bj * 128;

  // per-lane fragment base pointers (plane lh, row base)
  const char* pa = h1 + (size_t)lh * PLB + (size_t)(rowA0 + wr * 64 + l15) * 16;
  const char* pb = h2 + (size_t)lh * PLB + (size_t)(rowB0 + wc * 64 + l15) * 16;

  f32x4 acc[4][4];  // [n][m]
#pragma unroll
  for (int n = 0; n < 4; ++n)
#pragma unroll
    for (int m = 0; m < 4; ++m) acc[n][m] = (f32x4)0.f;
  float rowAcc[5][4];
#pragma unroll
  for (int d = 0; d < 5; ++d)
#pragma unroll
    for (int m = 0; m < 4; ++m) rowAcc[d][m] = 0.f;

#define EPI(DCP) do {                                                          \
    float s1K[4];                                                              \
    _Pragma("unroll")                                                          \
    for (int m = 0; m < 4; ++m)                                                \
      s1K[m] = inv1[(DCP) * N_ROWS + rowA0 + wr * 64 + m * 16 + l15] * KSC;    \
    _Pragma("unroll")                                                          \
    for (int n = 0; n < 4; ++n) {                                              \
      const f32x4 s2 = *(const f32x4*)(inv2 + (DCP) * N_ROWS + rowB0 +         \
                                       wc * 64 + n * 16 + (lh << 2));          \
      _Pragma("unroll")                                                        \
      for (int m = 0; m < 4; ++m) {                                            \
        const f32x4 u = acc[n][m] * s2 * s1K[m] + NEGSH;                       \
        rowAcc[(DCP)][m] += __builtin_amdgcn_exp2f(u[0]) +                     \
                            __builtin_amdgcn_exp2f(u[1]) +                     \
                            __builtin_amdgcn_exp2f(u[2]) +                     \
                            __builtin_amdgcn_exp2f(u[3]);                      \
      }                                                                        \
    }                                                                          \
    if (bi == bj && wr == wc && lh == (l15 >> 2)) {                            \
      const int rgd = l15 & 3;                                                 \
      _Pragma("unroll")                                                        \
      for (int m = 0; m < 4; ++m) {                                            \
        const float s2d = inv2[(DCP) * N_ROWS + rowB0 + wc * 64 + m * 16 + l15];\
        diag[(DCP) * N_ROWS + rowA0 + wr * 64 + m * 16 + l15] =                \
            acc[m][m][rgd] * s1K[m] * s2d * LN2;                               \
      }                                                                        \
    } } while (0)

#pragma unroll 1
  for (int ck = 0; ck < 6; ++ck) {
    longx2 a0[4], b0[4], a1[4], b1[4];
#pragma unroll
    for (int m = 0; m < 4; ++m) {
      a0[m] = *(const longx2*)(pa + m * 256);
      b0[m] = *(const longx2*)(pb + m * 256);
    }
#pragma unroll
    for (int m = 0; m < 4; ++m) {
      a1[m] = *(const longx2*)(pa + 4 * PLB + m * 256);
      b1[m] = *(const longx2*)(pb + 4 * PLB + m * 256);
    }
    // th = 0 (K += 64)
#pragma unroll
    for (int s = 0; s < 2; ++s)
#pragma unroll
      for (int n = 0; n < 4; ++n)
#pragma unroll
        for (int m = 0; m < 4; ++m)
          acc[n][m] = __builtin_amdgcn_mfma_f32_16x16x32_fp8_fp8(
              b0[n][s], a0[m][s], acc[n][m], 0, 0, 0);
    if (ck == 0) EPI(0);                       // K = 64
    // th = 1 (K += 64)
#pragma unroll
    for (int s = 0; s < 2; ++s)
#pragma unroll
      for (int n = 0; n < 4; ++n)
#pragma unroll
        for (int m = 0; m < 4; ++m)
          acc[n][m] = __builtin_amdgcn_mfma_f32_16x16x32_fp8_fp8(
              b1[n][s], a1[m][s], acc[n][m], 0, 0, 0);
    if (ck == 0)      EPI(1);                  // K = 128
    else if (ck == 1) EPI(2);                  // K = 256
    else if (ck == 3) EPI(3);                  // K = 512
    else if (ck == 5) EPI(4);                  // K = 768
    pa += 8 * PLB;
    pb += 8 * PLB;
  }
#undef EPI

  // butterfly over lane-hi (j sub-axis), combine wc halves via small LDS
#pragma unroll
  for (int d = 0; d < 5; ++d)
#pragma unroll
    for (int m = 0; m < 4; ++m) {
      float v = rowAcc[d][m];
      v += __shfl_xor(v, 16, 64);
      v += __shfl_xor(v, 32, 64);
      if (lh == 0) scr[wc][d][wr * 64 + m * 16 + l15] = v;
    }
  __syncthreads();
  for (int x = tid; x < 5 * 128; x += 256) {
    const int d = x >> 7, r = x & 127;
    partial[((size_t)bj * 5 + d) * N_ROWS + rowA0 + r] = scr[0][d][r] + scr[1][d][r];
  }
}

// ---------------- kernel 3: final reduction ----------------
__global__ __launch_bounds__(256) void mcl_reduce(
    const float* __restrict__ partial, const float* __restrict__ diag,
    float* __restrict__ out)
{
  const int item = blockIdx.x * 256 + threadIdx.x;  // 0..40959
  const int d = item >> 13;
  const int i = item & (N_ROWS - 1);
  float s = 0.f;
#pragma unroll 4
  for (int bj = 0; bj < 64; ++bj)
    s += partial[((size_t)bj * 5 + d) * N_ROWS + i];
  float term = (20.0f + logf(s) - diag[d * N_ROWS + i]) * (1.0f / 8192.0f);
#pragma unroll
  for (int off = 32; off > 0; off >>= 1) term += __shfl_down(term, off, 64);
  __shared__ float red[4];
  const int lane = threadIdx.x & 63, w = threadIdx.x >> 6;
  if (lane == 0) red[w] = term;
  __syncthreads();
  if (threadIdx.x == 0) atomicAdd(out, red[0] + red[1] + red[2] + red[3]);
}

// ---------------- launcher ----------------
extern "C" void kernel_launch(void* const* d_in, const int* in_sizes, int n_in,
                              void* d_out, int out_size, void* d_ws, size_t ws_size,
                              hipStream_t stream) {
  const float* e1 = (const float*)d_in[0];
  const float* e2 = (const float*)d_in[1];
  char* ws = (char*)d_ws;

  const size_t HBYTES = (size_t)N_ROWS * DFULL;                 // 6,291,456 (fp8)
  const size_t IBYTES = (size_t)5 * N_ROWS * sizeof(float);     //   163,840
  char*  h1      = ws;
  char*  h2      = ws + HBYTES;
  float* inv1    = (float*)(ws + 2 * HBYTES);
  float* inv2    = (float*)(ws + 2 * HBYTES + IBYTES);
  float* diag    = (float*)(ws + 2 * HBYTES + 2 * IBYTES);
  float* partial = (float*)(ws + 2 * HBYTES + 3 * IBYTES);      // 64*5*8192*4 = 10,485,760
  const size_t NEED = 2 * HBYTES + 3 * IBYTES + (size_t)64 * 5 * N_ROWS * sizeof(float);
  if (ws_size < NEED) return;

  hipMemsetAsync(d_out, 0, sizeof(float) * out_size, stream);
  mcl_prep<<<2 * N_ROWS, 192, 0, stream>>>(e1, e2, h1, h2, inv1, inv2);
  mcl_main<<<4096, 256, 0, stream>>>(h1, h2, inv1, inv2, diag, partial);
  mcl_reduce<<<160, 256, 0, stream>>>(partial, diag, (float*)d_out);
}

// Round 9
// 133.783 us; speedup vs baseline: 6.6582x; 1.0854x over previous
//
#include <hip/hip_runtime.h>
#include <math.h>

typedef __attribute__((ext_vector_type(4))) float f32x4;
typedef __attribute__((ext_vector_type(4))) int   i32x4;
typedef __attribute__((ext_vector_type(8))) int   i32x8;

#define N_ROWS 8192
#define DFULL 768
#define KSC (1.4426950408889634f / 0.05f)
#define NEGSH (-28.853900817779268f)   // -20 * log2(e)
#define LN2 0.6931471805599453f
#define PLB32 ((size_t)N_ROWS * 32)    // bytes per 32B-kblock plane

// ---------------- kernel 1: per-row prefix norms + fp8 e4m3 convert (32B-plane layout) ----
// Plane q = k>>5 holds, at row*32 + (k&31), the fp8 byte for (row,k). Lane (row, lh)
// of an MFMA fragment reads 32 consecutive bytes at plane (ck*4+lh) -> k = ck*128+lh*32+[0..31].
// Same layout for A and B => dot products invariant under any consistent HW k-permutation.
__global__ __launch_bounds__(192) void mcl_prep(
    const float* __restrict__ e1, const float* __restrict__ e2,
    char* __restrict__ h1, char* __restrict__ h2,
    float* __restrict__ inv1, float* __restrict__ inv2)
{
  const int b = blockIdx.x;
  const int mat = b >> 13, row = b & (N_ROWS - 1);
  const float* src = (mat ? e2 : e1) + (size_t)row * DFULL;
  char* dst = mat ? h2 : h1;
  float* invo = mat ? inv2 : inv1;
  const int t = threadIdx.x;
  const int k = t * 4;

  const f32x4 v = *(const f32x4*)(src + k);
  const float s = v[0]*v[0] + v[1]*v[1] + v[2]*v[2] + v[3]*v[3];
  float p0 = (k < 64)  ? s : 0.f;
  float p1 = (k < 128) ? s : 0.f;
  float p2 = (k < 256) ? s : 0.f;
  float p3 = (k < 512) ? s : 0.f;
  float p4 = s;

  const int lo = __builtin_amdgcn_cvt_pk_fp8_f32(v[0], v[1], 0, false);
  const int pk = __builtin_amdgcn_cvt_pk_fp8_f32(v[2], v[3], lo, true);
  *(int*)(dst + (size_t)(k >> 5) * PLB32 + (size_t)row * 32 + (k & 31)) = pk;

#pragma unroll
  for (int off = 32; off > 0; off >>= 1) {
    p0 += __shfl_down(p0, off, 64);
    p1 += __shfl_down(p1, off, 64);
    p2 += __shfl_down(p2, off, 64);
    p3 += __shfl_down(p3, off, 64);
    p4 += __shfl_down(p4, off, 64);
  }
  __shared__ float red[3][5];
  const int lane = t & 63, w = t >> 6;
  if (lane == 0) { red[w][0]=p0; red[w][1]=p1; red[w][2]=p2; red[w][3]=p3; red[w][4]=p4; }
  __syncthreads();
  if (t == 0) {
#pragma unroll
    for (int q = 0; q < 5; ++q) {
      const float sum = red[0][q] + red[1][q] + red[2][q];
      invo[q * N_ROWS + row] = 1.f / fmaxf(sqrtf(sum), 1e-8f);
    }
  }
}

// ---------------- kernel 2: MX-fp8 (K=128) GEMM + checkpoint softmax partials ------------
// 256 threads = 4 waves (2x2), per-wave 64x64, no staging/barriers in hot loop.
// mfma_scale_f32_16x16x128_f8f6f4, scales = 0x7F (1.0). K=64 checkpoint via extra
// scale-masked pass (lanes lh>=2 scale 0x00 -> their k>=64 contributions flush to 0 exactly).
// Swapped operands: acc[n][m] = mfma(bf[n], af[m], .) ->
//   i (softmax row) = wr*64 + m*16 + (lane&15)         [lane-low]
//   j (reduce axis) = wc*64 + n*16 + (lane>>4)*4 + rg  [register + lane-hi]
__global__ __launch_bounds__(256, 2) void mcl_main(
    const char* __restrict__ h1, const char* __restrict__ h2,
    const float* __restrict__ inv1, const float* __restrict__ inv2,
    float* __restrict__ diag, float* __restrict__ partial)
{
  __shared__ float rowsumW[2][5][128];   // [wc][dim][row], each slot written exactly once

  const int tid = threadIdx.x;
  const int lane = tid & 63, wid = tid >> 6;
  const int wr = wid >> 1, wc = wid & 1;
  const int l15 = lane & 15, lh = lane >> 4;

  // XCD-chunked + 8x8-supertile swizzle (bijective: 4096 = 8 * 512)
  const int id = blockIdx.x;
  const int nid = (id & 7) * 512 + (id >> 3);
  const int st = nid >> 6, tt = nid & 63;
  const int bi = ((st >> 3) << 3) + (tt >> 3);
  const int bj = ((st & 7) << 3) + (tt & 7);
  const int rowA0 = bi * 128, rowB0 = bj * 128;

  const char* pa = h1 + (size_t)lh * PLB32 + (size_t)(rowA0 + wr * 64 + l15) * 32;
  const char* pb = h2 + (size_t)lh * PLB32 + (size_t)(rowB0 + wc * 64 + l15) * 32;

  f32x4 acc[4][4];  // [n][m]
#pragma unroll
  for (int n = 0; n < 4; ++n)
#pragma unroll
    for (int m = 0; m < 4; ++m) acc[n][m] = (f32x4)0.f;

#define LOADF(DST, P) do {                                                     \
    const i32x4 lo_ = *(const i32x4*)(P);                                      \
    const i32x4 hi_ = *(const i32x4*)((P) + 16);                               \
    DST = __builtin_shufflevector(lo_, hi_, 0, 1, 2, 3, 4, 5, 6, 7); } while (0)

#define SUMEXP(RP, U) do {                                                     \
    RP += __builtin_amdgcn_exp2f((U)[0]) + __builtin_amdgcn_exp2f((U)[1]) +    \
          __builtin_amdgcn_exp2f((U)[2]) + __builtin_amdgcn_exp2f((U)[3]); } while (0)

#define REDUCE_STORE(RP, DCP) do {                                             \
    _Pragma("unroll")                                                          \
    for (int m = 0; m < 4; ++m) {                                              \
      float v_ = (RP)[m];                                                      \
      v_ += __shfl_xor(v_, 16, 64);                                            \
      v_ += __shfl_xor(v_, 32, 64);                                            \
      if (lh == 0) rowsumW[wc][(DCP)][wr * 64 + m * 16 + l15] = v_;            \
    } } while (0)

#define EPI(DCP) do {                                                          \
    float s1K[4];                                                              \
    _Pragma("unroll")                                                          \
    for (int m = 0; m < 4; ++m)                                                \
      s1K[m] = inv1[(DCP) * N_ROWS + rowA0 + wr * 64 + m * 16 + l15] * KSC;    \
    float rp[4] = {0.f, 0.f, 0.f, 0.f};                                        \
    _Pragma("unroll")                                                          \
    for (int n = 0; n < 4; ++n) {                                              \
      const f32x4 s2 = *(const f32x4*)(inv2 + (DCP) * N_ROWS + rowB0 +         \
                                       wc * 64 + n * 16 + (lh << 2));          \
      _Pragma("unroll")                                                        \
      for (int m = 0; m < 4; ++m) {                                            \
        const f32x4 u = acc[n][m] * s2 * s1K[m] + NEGSH;                       \
        SUMEXP(rp[m], u);                                                      \
      }                                                                        \
    }                                                                          \
    REDUCE_STORE(rp, (DCP));                                                   \
    if (bi == bj && wr == wc && lh == (l15 >> 2)) {                            \
      const int rgd = l15 & 3;                                                 \
      _Pragma("unroll")                                                        \
      for (int m = 0; m < 4; ++m) {                                            \
        const float s2d = inv2[(DCP) * N_ROWS + rowB0 + wc * 64 + m * 16 + l15];\
        diag[(DCP) * N_ROWS + rowA0 + wr * 64 + m * 16 + l15] =                \
            acc[m][m][rgd] * s1K[m] * s2d * LN2;                               \
      }                                                                        \
    } } while (0)

  // ---------------- chunk 0: masked K<64 pass (dcp0) + full pass (dcp1 at K=128) --------
  {
    i32x8 af[4], bf[4];
#pragma unroll
    for (int m = 0; m < 4; ++m) { LOADF(af[m], pa + m * 512); }
#pragma unroll
    for (int n = 0; n < 4; ++n) { LOADF(bf[n], pb + n * 512); }
    const int msk = (lh < 2) ? 0x7F : 0x00;   // e8m0: 1.0 for k<64 lanes, 2^-127 (->flush) else
    float s1K0[4], s1K1[4];
#pragma unroll
    for (int m = 0; m < 4; ++m) {
      s1K0[m] = inv1[0 * N_ROWS + rowA0 + wr * 64 + m * 16 + l15] * KSC;
      s1K1[m] = inv1[1 * N_ROWS + rowA0 + wr * 64 + m * 16 + l15] * KSC;
    }
    float rp0[4] = {0.f, 0.f, 0.f, 0.f};
    float rp1[4] = {0.f, 0.f, 0.f, 0.f};
#pragma unroll
    for (int n = 0; n < 4; ++n) {
      const f32x4 s20 = *(const f32x4*)(inv2 + 0 * N_ROWS + rowB0 + wc * 64 + n * 16 + (lh << 2));
      const f32x4 s21 = *(const f32x4*)(inv2 + 1 * N_ROWS + rowB0 + wc * 64 + n * 16 + (lh << 2));
#pragma unroll
      for (int m = 0; m < 4; ++m) {
        const f32x4 t = __builtin_amdgcn_mfma_scale_f32_16x16x128_f8f6f4(
            bf[n], af[m], (f32x4)0.f, 0, 0, 0, msk, 0, msk);
        acc[n][m] = __builtin_amdgcn_mfma_scale_f32_16x16x128_f8f6f4(
            bf[n], af[m], acc[n][m], 0, 0, 0, 0x7F, 0, 0x7F);
        const f32x4 u0 = t * s20 * s1K0[m] + NEGSH;
        SUMEXP(rp0[m], u0);
        const f32x4 u1 = acc[n][m] * s21 * s1K1[m] + NEGSH;
        SUMEXP(rp1[m], u1);
        if (n == m && bi == bj && wr == wc && lh == (l15 >> 2)) {
          const int rgd = l15 & 3;
          const float s2d0 = inv2[0 * N_ROWS + rowB0 + wc * 64 + m * 16 + l15];
          const float s2d1 = inv2[1 * N_ROWS + rowB0 + wc * 64 + m * 16 + l15];
          diag[0 * N_ROWS + rowA0 + wr * 64 + m * 16 + l15] = t[rgd] * s1K0[m] * s2d0 * LN2;
          diag[1 * N_ROWS + rowA0 + wr * 64 + m * 16 + l15] = acc[m][m][rgd] * s1K1[m] * s2d1 * LN2;
        }
      }
    }
    REDUCE_STORE(rp0, 0);
    REDUCE_STORE(rp1, 1);
    pa += 4 * PLB32;
    pb += 4 * PLB32;
  }

  // ---------------- chunks 1..5: full K=128 MFMAs + checkpoints at K=256/512/768 --------
#pragma unroll 1
  for (int ck = 1; ck < 6; ++ck) {
    i32x8 af[4], bf[4];
#pragma unroll
    for (int m = 0; m < 4; ++m) { LOADF(af[m], pa + m * 512); }
#pragma unroll
    for (int n = 0; n < 4; ++n) { LOADF(bf[n], pb + n * 512); }
    __builtin_amdgcn_s_setprio(1);
#pragma unroll
    for (int n = 0; n < 4; ++n)
#pragma unroll
      for (int m = 0; m < 4; ++m)
        acc[n][m] = __builtin_amdgcn_mfma_scale_f32_16x16x128_f8f6f4(
            bf[n], af[m], acc[n][m], 0, 0, 0, 0x7F, 0, 0x7F);
    __builtin_amdgcn_s_setprio(0);
    if (ck == 1)      EPI(2);   // K = 256
    else if (ck == 3) EPI(3);   // K = 512
    else if (ck == 5) EPI(4);   // K = 768
    pa += 4 * PLB32;
    pb += 4 * PLB32;
  }
#undef EPI
#undef REDUCE_STORE
#undef SUMEXP
#undef LOADF

  __syncthreads();
  for (int x = tid; x < 5 * 128; x += 256) {
    const int d = x >> 7, r = x & 127;
    partial[((size_t)bj * 5 + d) * N_ROWS + rowA0 + r] =
        rowsumW[0][d][r] + rowsumW[1][d][r];
  }
}

// ---------------- kernel 3: final reduction ----------------
__global__ __launch_bounds__(256) void mcl_reduce(
    const float* __restrict__ partial, const float* __restrict__ diag,
    float* __restrict__ out)
{
  const int item = blockIdx.x * 256 + threadIdx.x;  // 0..40959
  const int d = item >> 13;
  const int i = item & (N_ROWS - 1);
  float s = 0.f;
#pragma unroll 4
  for (int bj = 0; bj < 64; ++bj)
    s += partial[((size_t)bj * 5 + d) * N_ROWS + i];
  float term = (20.0f + logf(s) - diag[d * N_ROWS + i]) * (1.0f / 8192.0f);
#pragma unroll
  for (int off = 32; off > 0; off >>= 1) term += __shfl_down(term, off, 64);
  __shared__ float red[4];
  const int lane = threadIdx.x & 63, w = threadIdx.x >> 6;
  if (lane == 0) red[w] = term;
  __syncthreads();
  if (threadIdx.x == 0) atomicAdd(out, red[0] + red[1] + red[2] + red[3]);
}

// ---------------- launcher ----------------
extern "C" void kernel_launch(void* const* d_in, const int* in_sizes, int n_in,
                              void* d_out, int out_size, void* d_ws, size_t ws_size,
                              hipStream_t stream) {
  const float* e1 = (const float*)d_in[0];
  const float* e2 = (const float*)d_in[1];
  char* ws = (char*)d_ws;

  const size_t HBYTES = (size_t)N_ROWS * DFULL;                 // 6,291,456 (fp8)
  const size_t IBYTES = (size_t)5 * N_ROWS * sizeof(float);     //   163,840
  char*  h1      = ws;
  char*  h2      = ws + HBYTES;
  float* inv1    = (float*)(ws + 2 * HBYTES);
  float* inv2    = (float*)(ws + 2 * HBYTES + IBYTES);
  float* diag    = (float*)(ws + 2 * HBYTES + 2 * IBYTES);
  float* partial = (float*)(ws + 2 * HBYTES + 3 * IBYTES);      // 64*5*8192*4 = 10,485,760
  const size_t NEED = 2 * HBYTES + 3 * IBYTES + (size_t)64 * 5 * N_ROWS * sizeof(float);
  if (ws_size < NEED) return;

  hipMemsetAsync(d_out, 0, sizeof(float) * out_size, stream);
  mcl_prep<<<2 * N_ROWS, 192, 0, stream>>>(e1, e2, h1, h2, inv1, inv2);
  mcl_main<<<4096, 256, 0, stream>>>(h1, h2, inv1, inv2, diag, partial);
  mcl_reduce<<<160, 256, 0, stream>>>(partial, diag, (float*)d_out);
}

// Round 10
// 128.294 us; speedup vs baseline: 6.9431x; 1.0428x over previous
//
#include <hip/hip_runtime.h>
#include <math.h>

typedef __attribute__((ext_vector_type(4))) float f32x4;
typedef __attribute__((ext_vector_type(4))) int   i32x4;
typedef __attribute__((ext_vector_type(8))) int   i32x8;

#define N_ROWS 8192
#define DFULL 768
#define KSC (1.4426950408889634f / 0.05f)
#define NEGSH (-28.853900817779268f)   // -20 * log2(e)
#define LN2 0.6931471805599453f
#define PLB32 ((size_t)N_ROWS * 32)    // bytes per 32B-kblock plane

// ---------------- kernel 1: per-row prefix norms + fp8 e4m3 convert (32B-plane layout) ----
__global__ __launch_bounds__(192) void mcl_prep(
    const float* __restrict__ e1, const float* __restrict__ e2,
    char* __restrict__ h1, char* __restrict__ h2,
    float* __restrict__ inv1, float* __restrict__ inv2)
{
  const int b = blockIdx.x;
  const int mat = b >> 13, row = b & (N_ROWS - 1);
  const float* src = (mat ? e2 : e1) + (size_t)row * DFULL;
  char* dst = mat ? h2 : h1;
  float* invo = mat ? inv2 : inv1;
  const int t = threadIdx.x;
  const int k = t * 4;

  const f32x4 v = *(const f32x4*)(src + k);
  const float s = v[0]*v[0] + v[1]*v[1] + v[2]*v[2] + v[3]*v[3];
  float p0 = (k < 64)  ? s : 0.f;
  float p1 = (k < 128) ? s : 0.f;
  float p2 = (k < 256) ? s : 0.f;
  float p3 = (k < 512) ? s : 0.f;
  float p4 = s;

  const int lo = __builtin_amdgcn_cvt_pk_fp8_f32(v[0], v[1], 0, false);
  const int pk = __builtin_amdgcn_cvt_pk_fp8_f32(v[2], v[3], lo, true);
  *(int*)(dst + (size_t)(k >> 5) * PLB32 + (size_t)row * 32 + (k & 31)) = pk;

#pragma unroll
  for (int off = 32; off > 0; off >>= 1) {
    p0 += __shfl_down(p0, off, 64);
    p1 += __shfl_down(p1, off, 64);
    p2 += __shfl_down(p2, off, 64);
    p3 += __shfl_down(p3, off, 64);
    p4 += __shfl_down(p4, off, 64);
  }
  __shared__ float red[3][5];
  const int lane = t & 63, w = t >> 6;
  if (lane == 0) { red[w][0]=p0; red[w][1]=p1; red[w][2]=p2; red[w][3]=p3; red[w][4]=p4; }
  __syncthreads();
  if (t == 0) {
#pragma unroll
    for (int q = 0; q < 5; ++q) {
      const float sum = red[0][q] + red[1][q] + red[2][q];
      invo[q * N_ROWS + row] = 1.f / fmaxf(sqrtf(sum), 1e-8f);
    }
  }
}

// ---------------- kernel 2: MX-fp8 (K=128) GEMM + pipelined checkpoint softmax ----------
// Per-chunk pipeline exploiting vmcnt FIFO order:
//   [scale loads (oldest)] [16 fragment loads] [exp/reduce work: waits scales only
//    (vmcnt=16, fragments still in flight)] [MFMA: waits vmcnt 0]
// Swapped operands: acc[n][m] = mfma(bf[n], af[m], .) ->
//   i (softmax row) = wr*64 + m*16 + (lane&15)         [lane-low]
//   j (reduce axis) = wc*64 + n*16 + (lane>>4)*4 + rg  [register + lane-hi]
__global__ __launch_bounds__(256, 2) void mcl_main(
    const char* __restrict__ h1, const char* __restrict__ h2,
    const float* __restrict__ inv1, const float* __restrict__ inv2,
    float* __restrict__ diag, float* __restrict__ partial)
{
  __shared__ float rowsumW[2][5][128];   // [wc][dim][row], each slot written once

  const int tid = threadIdx.x;
  const int lane = tid & 63, wid = tid >> 6;
  const int wr = wid >> 1, wc = wid & 1;
  const int l15 = lane & 15, lh = lane >> 4;
  const int rgd = l15 & 3;

  // XCD-chunked + 8x8-supertile swizzle (bijective: 4096 = 8 * 512)
  const int id = blockIdx.x;
  const int nid = (id & 7) * 512 + (id >> 3);
  const int st = nid >> 6, tt = nid & 63;
  const int bi = ((st >> 3) << 3) + (tt >> 3);
  const int bj = ((st & 7) << 3) + (tt & 7);
  const int rowA0 = bi * 128, rowB0 = bj * 128;
  const bool dgb = (bi == bj) && (wr == wc) && (lh == (l15 >> 2));

  const char* pa = h1 + (size_t)lh * PLB32 + (size_t)(rowA0 + wr * 64 + l15) * 32;
  const char* pb = h2 + (size_t)lh * PLB32 + (size_t)(rowB0 + wc * 64 + l15) * 32;

  f32x4 acc[4][4];  // [n][m]
#pragma unroll
  for (int n = 0; n < 4; ++n)
#pragma unroll
    for (int m = 0; m < 4; ++m) acc[n][m] = (f32x4)0.f;

#define LOADF(CK) do {                                                         \
    _Pragma("unroll")                                                          \
    for (int m = 0; m < 4; ++m) {                                              \
      const i32x4 alo = *(const i32x4*)(pa + (CK) * 4 * PLB32 + m * 512);      \
      const i32x4 ahi = *(const i32x4*)(pa + (CK) * 4 * PLB32 + m * 512 + 16); \
      af[m] = __builtin_shufflevector(alo, ahi, 0, 1, 2, 3, 4, 5, 6, 7);       \
      const i32x4 blo = *(const i32x4*)(pb + (CK) * 4 * PLB32 + m * 512);      \
      const i32x4 bhi = *(const i32x4*)(pb + (CK) * 4 * PLB32 + m * 512 + 16); \
      bf[m] = __builtin_shufflevector(blo, bhi, 0, 1, 2, 3, 4, 5, 6, 7);       \
    } } while (0)

#define MFMACL(CK) do {                                                        \
    __builtin_amdgcn_s_setprio(1);                                             \
    _Pragma("unroll")                                                          \
    for (int n = 0; n < 4; ++n)                                                \
      _Pragma("unroll")                                                        \
      for (int m = 0; m < 4; ++m)                                              \
        acc[n][m] = __builtin_amdgcn_mfma_scale_f32_16x16x128_f8f6f4(          \
            bf[n], af[m], acc[n][m], 0, 0, 0, 0x7F, 0, 0x7F);                  \
    __builtin_amdgcn_s_setprio(0);                                             \
  } while (0)

#define SUMEXP(RP, U) do {                                                     \
    RP += __builtin_amdgcn_exp2f((U)[0]) + __builtin_amdgcn_exp2f((U)[1]) +    \
          __builtin_amdgcn_exp2f((U)[2]) + __builtin_amdgcn_exp2f((U)[3]); } while (0)

#define REDUCE_STORE(RP, DCP) do {                                             \
    _Pragma("unroll")                                                          \
    for (int m = 0; m < 4; ++m) {                                              \
      float v_ = (RP)[m];                                                      \
      v_ += __shfl_xor(v_, 16, 64);                                            \
      v_ += __shfl_xor(v_, 32, 64);                                            \
      if (lh == 0) rowsumW[wc][(DCP)][wr * 64 + m * 16 + l15] = v_;            \
    } } while (0)

// scale pre-load (issue BEFORE fragment loads so exps need only vmcnt(16))
#define EPIPRE(DCP, S1, S2) do {                                               \
    _Pragma("unroll")                                                          \
    for (int m = 0; m < 4; ++m)                                                \
      S1[m] = inv1[(DCP) * N_ROWS + rowA0 + wr * 64 + m * 16 + l15] * KSC;     \
    _Pragma("unroll")                                                          \
    for (int n = 0; n < 4; ++n)                                                \
      S2[n] = *(const f32x4*)(inv2 + (DCP) * N_ROWS + rowB0 + wc * 64 +        \
                              n * 16 + (lh << 2));                             \
  } while (0)

// exp + reduce + diag from current acc (scales already resident)
#define EPIMAIN(DCP, S1, S2) do {                                              \
    float rp[4] = {0.f, 0.f, 0.f, 0.f};                                        \
    _Pragma("unroll")                                                          \
    for (int n = 0; n < 4; ++n)                                                \
      _Pragma("unroll")                                                        \
      for (int m = 0; m < 4; ++m) {                                            \
        const f32x4 u = acc[n][m] * S2[n] * S1[m] + NEGSH;                     \
        SUMEXP(rp[m], u);                                                      \
      }                                                                        \
    REDUCE_STORE(rp, (DCP));                                                   \
    if (dgb) {                                                                 \
      _Pragma("unroll")                                                        \
      for (int m = 0; m < 4; ++m)                                              \
        diag[(DCP) * N_ROWS + rowA0 + wr * 64 + m * 16 + l15] =                \
            acc[m][m][rgd] * S1[m] * S2[m][rgd] * LN2;                         \
    } } while (0)

  i32x8 af[4], bf[4];

  // ---------------- chunk 0: masked K<64 pass (dcp0) fused per-n; dcp1 deferred --------
  {
    float s1a[4]; f32x4 s2a[4];
    EPIPRE(0, s1a, s2a);
    LOADF(0);
    const int msk = (lh < 2) ? 0x7F : 0x00;   // e8m0: 1.0 for k<64 lanes, flush-to-0 else
    float rp0[4] = {0.f, 0.f, 0.f, 0.f};
#pragma unroll
    for (int n = 0; n < 4; ++n) {
      f32x4 t[4];
#pragma unroll
      for (int m = 0; m < 4; ++m)
        t[m] = __builtin_amdgcn_mfma_scale_f32_16x16x128_f8f6f4(
            bf[n], af[m], (f32x4)0.f, 0, 0, 0, msk, 0, msk);
#pragma unroll
      for (int m = 0; m < 4; ++m)
        acc[n][m] = __builtin_amdgcn_mfma_scale_f32_16x16x128_f8f6f4(
            bf[n], af[m], acc[n][m], 0, 0, 0, 0x7F, 0, 0x7F);
#pragma unroll
      for (int m = 0; m < 4; ++m) {
        const f32x4 u0 = t[m] * s2a[n] * s1a[m] + NEGSH;
        SUMEXP(rp0[m], u0);
      }
      if (dgb)
        diag[0 * N_ROWS + rowA0 + wr * 64 + n * 16 + l15] =
            t[n][rgd] * s1a[n] * s2a[n][rgd] * LN2;
    }
    REDUCE_STORE(rp0, 0);
  }

  // ---------------- chunk 1: dcp1 exps in chunk-1 load shadow; MFMA; then dcp2 --------
  {
    float s1b[4]; f32x4 s2b[4];
    EPIPRE(1, s1b, s2b);
    LOADF(1);
    EPIMAIN(1, s1b, s2b);
    MFMACL(1);
  }
  // ---------------- chunk 2: dcp2 (K=256) exps in chunk-2 load shadow ----------------
  {
    float s1c[4]; f32x4 s2c[4];
    EPIPRE(2, s1c, s2c);
    LOADF(2);
    EPIMAIN(2, s1c, s2c);
    MFMACL(2);
  }
  // ---------------- chunk 3 (no checkpoint) ------------------------------------------
  {
    LOADF(3);
    MFMACL(3);
  }
  // ---------------- chunk 4: dcp3 (K=512) exps in chunk-4 load shadow ----------------
  {
    float s1d[4]; f32x4 s2d4[4];
    EPIPRE(3, s1d, s2d4);
    LOADF(4);
    EPIMAIN(3, s1d, s2d4);
    MFMACL(4);
  }
  // ---------------- chunk 5 + final checkpoint dcp4 (K=768) --------------------------
  {
    float s1e[4]; f32x4 s2e[4];
    EPIPRE(4, s1e, s2e);
    LOADF(5);
    MFMACL(5);
    EPIMAIN(4, s1e, s2e);
  }

#undef EPIMAIN
#undef EPIPRE
#undef REDUCE_STORE
#undef SUMEXP
#undef MFMACL
#undef LOADF

  __syncthreads();
  for (int x = tid; x < 5 * 128; x += 256) {
    const int d = x >> 7, r = x & 127;
    partial[((size_t)bj * 5 + d) * N_ROWS + rowA0 + r] =
        rowsumW[0][d][r] + rowsumW[1][d][r];
  }
}

// ---------------- kernel 3: final reduction ----------------
__global__ __launch_bounds__(256) void mcl_reduce(
    const float* __restrict__ partial, const float* __restrict__ diag,
    float* __restrict__ out)
{
  const int item = blockIdx.x * 256 + threadIdx.x;  // 0..40959
  const int d = item >> 13;
  const int i = item & (N_ROWS - 1);
  float s = 0.f;
#pragma unroll 4
  for (int bj = 0; bj < 64; ++bj)
    s += partial[((size_t)bj * 5 + d) * N_ROWS + i];
  float term = (20.0f + logf(s) - diag[d * N_ROWS + i]) * (1.0f / 8192.0f);
#pragma unroll
  for (int off = 32; off > 0; off >>= 1) term += __shfl_down(term, off, 64);
  __shared__ float red[4];
  const int lane = threadIdx.x & 63, w = threadIdx.x >> 6;
  if (lane == 0) red[w] = term;
  __syncthreads();
  if (threadIdx.x == 0) atomicAdd(out, red[0] + red[1] + red[2] + red[3]);
}

// ---------------- launcher ----------------
extern "C" void kernel_launch(void* const* d_in, const int* in_sizes, int n_in,
                              void* d_out, int out_size, void* d_ws, size_t ws_size,
                              hipStream_t stream) {
  const float* e1 = (const float*)d_in[0];
  const float* e2 = (const float*)d_in[1];
  char* ws = (char*)d_ws;

  const size_t HBYTES = (size_t)N_ROWS * DFULL;                 // 6,291,456 (fp8)
  const size_t IBYTES = (size_t)5 * N_ROWS * sizeof(float);     //   163,840
  char*  h1      = ws;
  char*  h2      = ws + HBYTES;
  float* inv1    = (float*)(ws + 2 * HBYTES);
  float* inv2    = (float*)(ws + 2 * HBYTES + IBYTES);
  float* diag    = (float*)(ws + 2 * HBYTES + 2 * IBYTES);
  float* partial = (float*)(ws + 2 * HBYTES + 3 * IBYTES);      // 64*5*8192*4 = 10,485,760
  const size_t NEED = 2 * HBYTES + 3 * IBYTES + (size_t)64 * 5 * N_ROWS * sizeof(float);
  if (ws_size < NEED) return;

  hipMemsetAsync(d_out, 0, sizeof(float) * out_size, stream);
  mcl_prep<<<2 * N_ROWS, 192, 0, stream>>>(e1, e2, h1, h2, inv1, inv2);
  mcl_main<<<4096, 256, 0, stream>>>(h1, h2, inv1, inv2, diag, partial);
  mcl_reduce<<<160, 256, 0, stream>>>(partial, diag, (float*)d_out);
}